// Round 1
// baseline (728.627 us; speedup 1.0000x reference)
//
#include <hip/hip_runtime.h>
#include <math.h>

// VQ-AE forward, fp32 baseline.
// N=65536, Din=512, H=128, D=32, K=1024. Output: single f32 scalar.
// ws layout: acc[1024] f32 | topics[65536] i32 | z[65536*32] f32 | h[65536*128] f32 (~42.2 MB)
// acc: [0..127] sum1, [128..255] sumsq1, [256..383] sum2, [384..511] sumsq2, [512] min-dist sum, [513] sq-diff sum

#define NROWS 65536

__global__ __launch_bounds__(256) void k_init(float* acc) {
    acc[(blockIdx.x << 8) + threadIdx.x] = 0.f;
}

// -------- GEMM1: h1 = X[65536,512] @ w1[512,128] + b1 --------
// BM=32, BN=128, BK=32. 256 thr: ty=tid>>5 (rows ty*4+i), tx=tid&31 (cols tx*4+j).
__global__ __launch_bounds__(256) void k_enc1(const float* __restrict__ X,
                                              const float* __restrict__ w1,
                                              const float* __restrict__ b1,
                                              float* __restrict__ h1) {
    __shared__ float As[32 * 36];   // [k][r], pad 36: read b128 @ As[k][ty*4] broadcast, conflict-free
    __shared__ float Bs[32 * 128];  // [k][c]
    const int tid = threadIdx.x;
    const int row0 = blockIdx.x << 5;
    const int ty = tid >> 5, tx = tid & 31;
    float4 c0 = {0.f,0.f,0.f,0.f}, c1 = c0, c2 = c0, c3 = c0;
    const int sr = tid >> 3, sk4 = tid & 7;  // staging: 8 full 128B lines per wave (coalesced)

    for (int k0 = 0; k0 < 512; k0 += 32) {
        __syncthreads();
        {
            float4 v = *(const float4*)(X + (size_t)(row0 + sr) * 512 + k0 + (sk4 << 2));
            const int kb = sk4 << 2;
            As[(kb + 0) * 36 + sr] = v.x;
            As[(kb + 1) * 36 + sr] = v.y;
            As[(kb + 2) * 36 + sr] = v.z;
            As[(kb + 3) * 36 + sr] = v.w;
        }
#pragma unroll
        for (int i = 0; i < 4; i++) {
            int idx = (i << 8) + tid;
            int kk = idx >> 5, c4 = idx & 31;
            *(float4*)&Bs[kk * 128 + (c4 << 2)] =
                *(const float4*)(w1 + (size_t)(k0 + kk) * 128 + (c4 << 2));
        }
        __syncthreads();
#pragma unroll 8
        for (int k = 0; k < 32; k++) {
            const float4 av = *(const float4*)&As[k * 36 + (ty << 2)];
            const float4 bv = *(const float4*)&Bs[k * 128 + (tx << 2)];
            c0.x = fmaf(av.x, bv.x, c0.x); c0.y = fmaf(av.x, bv.y, c0.y);
            c0.z = fmaf(av.x, bv.z, c0.z); c0.w = fmaf(av.x, bv.w, c0.w);
            c1.x = fmaf(av.y, bv.x, c1.x); c1.y = fmaf(av.y, bv.y, c1.y);
            c1.z = fmaf(av.y, bv.z, c1.z); c1.w = fmaf(av.y, bv.w, c1.w);
            c2.x = fmaf(av.z, bv.x, c2.x); c2.y = fmaf(av.z, bv.y, c2.y);
            c2.z = fmaf(av.z, bv.z, c2.z); c2.w = fmaf(av.z, bv.w, c2.w);
            c3.x = fmaf(av.w, bv.x, c3.x); c3.y = fmaf(av.w, bv.y, c3.y);
            c3.z = fmaf(av.w, bv.z, c3.z); c3.w = fmaf(av.w, bv.w, c3.w);
        }
    }
    const float4 bias = *(const float4*)(b1 + (tx << 2));
    const int rbase = row0 + (ty << 2);
    float4 o;
    o.x = c0.x + bias.x; o.y = c0.y + bias.y; o.z = c0.z + bias.z; o.w = c0.w + bias.w;
    *(float4*)(h1 + (size_t)(rbase + 0) * 128 + (tx << 2)) = o;
    o.x = c1.x + bias.x; o.y = c1.y + bias.y; o.z = c1.z + bias.z; o.w = c1.w + bias.w;
    *(float4*)(h1 + (size_t)(rbase + 1) * 128 + (tx << 2)) = o;
    o.x = c2.x + bias.x; o.y = c2.y + bias.y; o.z = c2.z + bias.z; o.w = c2.w + bias.w;
    *(float4*)(h1 + (size_t)(rbase + 2) * 128 + (tx << 2)) = o;
    o.x = c3.x + bias.x; o.y = c3.y + bias.y; o.z = c3.z + bias.z; o.w = c3.w + bias.w;
    *(float4*)(h1 + (size_t)(rbase + 3) * 128 + (tx << 2)) = o;
}

// -------- per-column sum / sumsq over h[65536,128] --------
__global__ __launch_bounds__(256) void k_bnstats(const float* __restrict__ h,
                                                 float* __restrict__ sums) {
    __shared__ float red[512];
    const int tid = threadIdx.x;
    const int gid = (blockIdx.x << 8) + tid;
    float s = 0.f, ss = 0.f;
    for (int i = gid; i < 65536 * 128; i += 512 * 256) {  // stride % 128 == 0 -> fixed column
        float v = h[i];
        s += v;
        ss = fmaf(v, v, ss);
    }
    red[tid] = s;
    red[256 + tid] = ss;
    __syncthreads();
    if (tid < 128) {
        atomicAdd(&sums[tid], red[tid] + red[tid + 128]);
        atomicAdd(&sums[128 + tid], red[256 + tid] + red[256 + tid + 128]);
    }
}

// -------- z = relu(bn(h1)) @ w2[128,32] + b2 --------
// 32 rows/block; thread: r=tid>>3 (0..31), c4=tid&7 -> 4 cols.
__global__ __launch_bounds__(256) void k_enc2(const float* __restrict__ h1,
                                              const float* __restrict__ acc,
                                              const float* __restrict__ g1,
                                              const float* __restrict__ be1,
                                              const float* __restrict__ w2,
                                              const float* __restrict__ b2,
                                              float* __restrict__ z) {
    __shared__ float Ws[128 * 32];
    __shared__ float Ar[32 * 132];  // pad 132: conflict-free stage writes and reads
    const int tid = threadIdx.x;
    for (int i = tid; i < 4096; i += 256) Ws[i] = w2[i];
    const int k4 = tid & 31;
    float scl[4], shf[4];
#pragma unroll
    for (int j = 0; j < 4; j++) {
        int k = (k4 << 2) + j;
        float mu = acc[k] * (1.f / 65536.f);
        float var = fmaf(-mu, mu, acc[128 + k] * (1.f / 65536.f));
        float s = g1[k] * rsqrtf(var + 1e-5f);
        scl[j] = s;
        shf[j] = fmaf(-mu, s, be1[k]);
    }
    __syncthreads();
    const int row0 = blockIdx.x << 5;
#pragma unroll
    for (int i = 0; i < 4; i++) {
        int idx = (i << 8) + tid;
        int r = idx >> 5;
        float4 v = *(const float4*)(h1 + (size_t)(row0 + r) * 128 + (k4 << 2));
        v.x = fmaxf(fmaf(v.x, scl[0], shf[0]), 0.f);
        v.y = fmaxf(fmaf(v.y, scl[1], shf[1]), 0.f);
        v.z = fmaxf(fmaf(v.z, scl[2], shf[2]), 0.f);
        v.w = fmaxf(fmaf(v.w, scl[3], shf[3]), 0.f);
        *(float4*)&Ar[r * 132 + (k4 << 2)] = v;
    }
    __syncthreads();
    const int r = tid >> 3, c4 = tid & 7;
    float4 a4 = {0.f,0.f,0.f,0.f};
#pragma unroll 8
    for (int k = 0; k < 128; k++) {
        const float a = Ar[r * 132 + k];
        const float4 w = *(const float4*)&Ws[k * 32 + (c4 << 2)];
        a4.x = fmaf(a, w.x, a4.x); a4.y = fmaf(a, w.y, a4.y);
        a4.z = fmaf(a, w.z, a4.z); a4.w = fmaf(a, w.w, a4.w);
    }
    const float4 bias = *(const float4*)(b2 + (c4 << 2));
    a4.x += bias.x; a4.y += bias.y; a4.z += bias.z; a4.w += bias.w;
    *(float4*)(z + (size_t)(row0 + r) * 32 + (c4 << 2)) = a4;
}

// -------- quantize: per row argmin_k ||z-c_k||^2, sum of mins --------
__global__ __launch_bounds__(256) void k_quant(const float* __restrict__ z,
                                               const float* __restrict__ cb,
                                               int* __restrict__ topics,
                                               float* accum) {
    __shared__ float Cs[256 * 36];
    __shared__ float Cn[256];
    __shared__ float red[256];
    const int tid = threadIdx.x;
    const size_t n = ((size_t)blockIdx.x << 8) + tid;
    float zr[32];
#pragma unroll
    for (int i = 0; i < 8; i++)
        *(float4*)&zr[i * 4] = *(const float4*)(z + n * 32 + i * 4);
    float zn = 0.f;
#pragma unroll
    for (int j = 0; j < 32; j++) zn = fmaf(zr[j], zr[j], zn);

    float best = 3.4e38f;
    int bestk = 0;
    for (int k0 = 0; k0 < 1024; k0 += 256) {
        __syncthreads();
#pragma unroll
        for (int i = 0; i < 8; i++) {
            int idx = (i << 8) + tid;
            int kk = idx >> 3, c4 = idx & 7;
            float4 v = *(const float4*)(cb + (size_t)(k0 + kk) * 32 + (c4 << 2));
            *(float4*)&Cs[kk * 36 + (c4 << 2)] = v;
            float pn = v.x * v.x + v.y * v.y + v.z * v.z + v.w * v.w;
            pn += __shfl_xor(pn, 1);
            pn += __shfl_xor(pn, 2);
            pn += __shfl_xor(pn, 4);
            if ((tid & 7) == 0) Cn[kk] = pn;
        }
        __syncthreads();
        for (int kk = 0; kk < 256; kk++) {
            float d = 0.f;
#pragma unroll
            for (int i = 0; i < 8; i++) {
                const float4 c = *(const float4*)&Cs[kk * 36 + (i << 2)];
                d = fmaf(zr[i * 4 + 0], c.x, d);
                d = fmaf(zr[i * 4 + 1], c.y, d);
                d = fmaf(zr[i * 4 + 2], c.z, d);
                d = fmaf(zr[i * 4 + 3], c.w, d);
            }
            float dist = zn + Cn[kk] - 2.f * d;
            if (dist < best) { best = dist; bestk = k0 + kk; }  // strict < keeps first index (argmin semantics)
        }
    }
    topics[n] = bestk;
    red[tid] = best;
    __syncthreads();
    for (int s = 128; s > 0; s >>= 1) {
        if (tid < s) red[tid] += red[tid + s];
        __syncthreads();
    }
    if (tid == 0) atomicAdd(accum + 512, red[0]);
}

// -------- h2 = codebook[topics] @ dw1[32,128] + db1 --------
__global__ __launch_bounds__(256) void k_dec1(const float* __restrict__ cb,
                                              const int* __restrict__ topics,
                                              const float* __restrict__ w1,
                                              const float* __restrict__ b1,
                                              float* __restrict__ h2) {
    __shared__ float Ws[32 * 128];
    __shared__ float Qs[8 * 33];
    const int tid = threadIdx.x;
    for (int i = tid; i < 4096; i += 256) Ws[i] = w1[i];
    const int rl = tid >> 5, c4 = tid & 31;
    const float4 bias = *(const float4*)(b1 + (c4 << 2));
    const int row0 = blockIdx.x << 6;
    for (int pass = 0; pass < 8; pass++) {
        const int rbase = row0 + (pass << 3);
        __syncthreads();
        Qs[rl * 33 + c4] = cb[(size_t)topics[rbase + rl] * 32 + c4];
        __syncthreads();
        float4 a4 = {0.f,0.f,0.f,0.f};
#pragma unroll
        for (int j = 0; j < 32; j++) {
            const float q = Qs[rl * 33 + j];
            const float4 w = *(const float4*)&Ws[j * 128 + (c4 << 2)];
            a4.x = fmaf(q, w.x, a4.x); a4.y = fmaf(q, w.y, a4.y);
            a4.z = fmaf(q, w.z, a4.z); a4.w = fmaf(q, w.w, a4.w);
        }
        a4.x += bias.x; a4.y += bias.y; a4.z += bias.z; a4.w += bias.w;
        *(float4*)(h2 + (size_t)(rbase + rl) * 128 + (c4 << 2)) = a4;
    }
}

// -------- X_ = relu(bn(h2)) @ dw2[128,512] + db2 ; accumulate sum((X_-X)^2) --------
// BM=64, BN=64, BK=128 (full K). 16x16 threads, TM=TN=4.
__global__ __launch_bounds__(256) void k_dec2(const float* __restrict__ h2,
                                              const float* acc,
                                              const float* __restrict__ g,
                                              const float* __restrict__ be,
                                              const float* __restrict__ w2,
                                              const float* __restrict__ b2,
                                              const float* __restrict__ X) {
    __shared__ float As[128 * 68];  // [k][r] transposed, pad 68
    __shared__ float Bs[128 * 68];  // [k][c], pad 68
    __shared__ float scl_s[128], shf_s[128];
    __shared__ float red[256];
    const int tid = threadIdx.x;
    if (tid < 128) {
        float mu = acc[256 + tid] * (1.f / 65536.f);
        float var = fmaf(-mu, mu, acc[384 + tid] * (1.f / 65536.f));
        float s = g[tid] * rsqrtf(var + 1e-5f);
        scl_s[tid] = s;
        shf_s[tid] = fmaf(-mu, s, be[tid]);
    }
    const int row0 = blockIdx.x << 6;
    const int col0 = blockIdx.y << 6;
    __syncthreads();
#pragma unroll
    for (int i = 0; i < 8; i++) {  // stage A with BN+ReLU (coalesced global: 2 rows/wave)
        int idx = (i << 8) + tid;
        int r = idx >> 5, k4 = idx & 31;
        float4 v = *(const float4*)(h2 + (size_t)(row0 + r) * 128 + (k4 << 2));
        const int kb = k4 << 2;
        v.x = fmaxf(fmaf(v.x, scl_s[kb + 0], shf_s[kb + 0]), 0.f);
        v.y = fmaxf(fmaf(v.y, scl_s[kb + 1], shf_s[kb + 1]), 0.f);
        v.z = fmaxf(fmaf(v.z, scl_s[kb + 2], shf_s[kb + 2]), 0.f);
        v.w = fmaxf(fmaf(v.w, scl_s[kb + 3], shf_s[kb + 3]), 0.f);
        As[(kb + 0) * 68 + r] = v.x;
        As[(kb + 1) * 68 + r] = v.y;
        As[(kb + 2) * 68 + r] = v.z;
        As[(kb + 3) * 68 + r] = v.w;
    }
#pragma unroll
    for (int i = 0; i < 8; i++) {  // stage B
        int idx = (i << 8) + tid;
        int kk = idx >> 4, c4 = idx & 15;
        *(float4*)&Bs[kk * 68 + (c4 << 2)] =
            *(const float4*)(w2 + (size_t)kk * 512 + col0 + (c4 << 2));
    }
    __syncthreads();
    const int ty = tid >> 4, tx = tid & 15;
    float4 c0 = {0.f,0.f,0.f,0.f}, c1 = c0, c2 = c0, c3 = c0;
#pragma unroll 8
    for (int k = 0; k < 128; k++) {
        const float4 av = *(const float4*)&As[k * 68 + (ty << 2)];
        const float4 bv = *(const float4*)&Bs[k * 68 + (tx << 2)];
        c0.x = fmaf(av.x, bv.x, c0.x); c0.y = fmaf(av.x, bv.y, c0.y);
        c0.z = fmaf(av.x, bv.z, c0.z); c0.w = fmaf(av.x, bv.w, c0.w);
        c1.x = fmaf(av.y, bv.x, c1.x); c1.y = fmaf(av.y, bv.y, c1.y);
        c1.z = fmaf(av.y, bv.z, c1.z); c1.w = fmaf(av.y, bv.w, c1.w);
        c2.x = fmaf(av.z, bv.x, c2.x); c2.y = fmaf(av.z, bv.y, c2.y);
        c2.z = fmaf(av.z, bv.z, c2.z); c2.w = fmaf(av.z, bv.w, c2.w);
        c3.x = fmaf(av.w, bv.x, c3.x); c3.y = fmaf(av.w, bv.y, c3.y);
        c3.z = fmaf(av.w, bv.z, c3.z); c3.w = fmaf(av.w, bv.w, c3.w);
    }
    const float4 bias = *(const float4*)(b2 + col0 + (tx << 2));
    float lsum = 0.f;
    {
        const float4 xv = *(const float4*)(X + (size_t)(row0 + (ty << 2) + 0) * 512 + col0 + (tx << 2));
        float d;
        d = c0.x + bias.x - xv.x; lsum = fmaf(d, d, lsum);
        d = c0.y + bias.y - xv.y; lsum = fmaf(d, d, lsum);
        d = c0.z + bias.z - xv.z; lsum = fmaf(d, d, lsum);
        d = c0.w + bias.w - xv.w; lsum = fmaf(d, d, lsum);
    }
    {
        const float4 xv = *(const float4*)(X + (size_t)(row0 + (ty << 2) + 1) * 512 + col0 + (tx << 2));
        float d;
        d = c1.x + bias.x - xv.x; lsum = fmaf(d, d, lsum);
        d = c1.y + bias.y - xv.y; lsum = fmaf(d, d, lsum);
        d = c1.z + bias.z - xv.z; lsum = fmaf(d, d, lsum);
        d = c1.w + bias.w - xv.w; lsum = fmaf(d, d, lsum);
    }
    {
        const float4 xv = *(const float4*)(X + (size_t)(row0 + (ty << 2) + 2) * 512 + col0 + (tx << 2));
        float d;
        d = c2.x + bias.x - xv.x; lsum = fmaf(d, d, lsum);
        d = c2.y + bias.y - xv.y; lsum = fmaf(d, d, lsum);
        d = c2.z + bias.z - xv.z; lsum = fmaf(d, d, lsum);
        d = c2.w + bias.w - xv.w; lsum = fmaf(d, d, lsum);
    }
    {
        const float4 xv = *(const float4*)(X + (size_t)(row0 + (ty << 2) + 3) * 512 + col0 + (tx << 2));
        float d;
        d = c3.x + bias.x - xv.x; lsum = fmaf(d, d, lsum);
        d = c3.y + bias.y - xv.y; lsum = fmaf(d, d, lsum);
        d = c3.z + bias.z - xv.z; lsum = fmaf(d, d, lsum);
        d = c3.w + bias.w - xv.w; lsum = fmaf(d, d, lsum);
    }
    red[tid] = lsum;
    __syncthreads();
    for (int s = 128; s > 0; s >>= 1) {
        if (tid < s) red[tid] += red[tid + s];
        __syncthreads();
    }
    if (tid == 0) atomicAdd((float*)acc + 513, red[0]);
}

__global__ void k_final(const float* __restrict__ acc, float* __restrict__ out) {
    if (threadIdx.x == 0) out[0] = 2.f * acc[512] + sqrtf(acc[513]);
}

extern "C" void kernel_launch(void* const* d_in, const int* in_sizes, int n_in,
                              void* d_out, int out_size, void* d_ws, size_t ws_size,
                              hipStream_t stream) {
    const float* X       = (const float*)d_in[0];
    const float* enc_w1  = (const float*)d_in[1];
    const float* enc_b1  = (const float*)d_in[2];
    const float* enc_g1  = (const float*)d_in[3];
    const float* enc_be1 = (const float*)d_in[4];
    const float* enc_w2  = (const float*)d_in[5];
    const float* enc_b2  = (const float*)d_in[6];
    const float* dec_w1  = (const float*)d_in[7];
    const float* dec_b1  = (const float*)d_in[8];
    const float* dec_g1  = (const float*)d_in[9];
    const float* dec_be1 = (const float*)d_in[10];
    const float* dec_w2  = (const float*)d_in[11];
    const float* dec_b2  = (const float*)d_in[12];
    const float* cb      = (const float*)d_in[13];
    float* out = (float*)d_out;

    float* acc    = (float*)d_ws;               // 1024 floats
    int*   topics = (int*)(acc + 1024);         // 65536 ints
    float* z      = (float*)(topics + 65536);   // 65536*32
    float* h      = z + (size_t)65536 * 32;     // 65536*128 (h1, then reused as h2)

    k_init<<<4, 256, 0, stream>>>(acc);
    k_enc1<<<2048, 256, 0, stream>>>(X, enc_w1, enc_b1, h);
    k_bnstats<<<512, 256, 0, stream>>>(h, acc);
    k_enc2<<<2048, 256, 0, stream>>>(h, acc, enc_g1, enc_be1, enc_w2, enc_b2, z);
    k_quant<<<256, 256, 0, stream>>>(z, cb, topics, acc);
    k_dec1<<<1024, 256, 0, stream>>>(cb, topics, dec_w1, dec_b1, h);
    k_bnstats<<<512, 256, 0, stream>>>(h, acc + 256);
    k_dec2<<<dim3(1024, 8), 256, 0, stream>>>(h, acc, dec_g1, dec_be1, dec_w2, dec_b2, X);
    k_final<<<1, 64, 0, stream>>>(acc, out);
}

// Round 2
// 407.286 us; speedup vs baseline: 1.7890x; 1.7890x over previous
//
#include <hip/hip_runtime.h>
#include <math.h>

// VQ-AE forward, bf16-MFMA version.
// N=65536, Din=512, H=128, D=32, K=1024. Output: single f32 scalar.
// ws layout: acc[1024] f32 | topics[65536] i32 | z[65536*32] f32 | h[65536*128] f32
// acc: [0..127] sum1, [128..255] sumsq1, [256..383] sum2, [384..511] sumsq2,
//      [512] min-dist sum, [513] sq-diff sum

typedef __attribute__((ext_vector_type(8))) short bf8;
typedef __attribute__((ext_vector_type(4))) float f4a;

__device__ __forceinline__ unsigned short f2bf(float f) {
    unsigned u = __float_as_uint(f);
    u += 0x7fffu + ((u >> 16) & 1u);   // RNE
    return (unsigned short)(u >> 16);
}
__device__ __forceinline__ unsigned pack2(float a, float b) {
    return (unsigned)f2bf(a) | ((unsigned)f2bf(b) << 16);
}

__global__ __launch_bounds__(256) void k_init(float* acc) {
    acc[(blockIdx.x << 8) + threadIdx.x] = 0.f;
}

// -------- GEMM1 (MFMA): h1[65536,128] = X[65536,512]@w1[512,128] + b1 --------
// Block: 256 thr (4 waves), tile 128M x 128N, BK=64 (8 chunks).
__global__ __launch_bounds__(256) void k_enc1(const float* __restrict__ X,
                                              const float* __restrict__ w1,
                                              const float* __restrict__ b1,
                                              float* __restrict__ h1) {
    __shared__ unsigned short As[128 * 72];  // [m][k], stride 72 (144B, 16B-mult; frag reads 2-way=free)
    __shared__ unsigned short Bs[128 * 72];  // [n][k] (w1 transposed during staging)
    const int t = threadIdx.x;
    const int row0 = blockIdx.x << 7;
    const int w = t >> 6, lane = t & 63, quad = lane >> 4, lcol = lane & 15;
    f4a acc[2][8];
#pragma unroll
    for (int i = 0; i < 2; i++)
#pragma unroll
        for (int j = 0; j < 8; j++) acc[i][j] = (f4a){0.f, 0.f, 0.f, 0.f};

    const int bn = t & 127, bkg = t >> 7;  // B staging coords
    for (int c = 0; c < 8; ++c) {
        const int k0 = c << 6;
        __syncthreads();
        // A: 128 rows x 64 k fp32 -> bf16 (row-major already A-layout, no transpose)
#pragma unroll
        for (int i = 0; i < 8; ++i) {
            int fidx = (i << 8) + t;
            int r = fidx >> 4, kq = (fidx & 15) << 2;
            float4 v = *(const float4*)(X + (size_t)(row0 + r) * 512 + k0 + kq);
            *(uint2*)&As[r * 72 + kq] = make_uint2(pack2(v.x, v.y), pack2(v.z, v.w));
        }
        // B: w1 chunk [64k][128n] -> Bs[n][k] (transpose; 4 coalesced dword loads -> 1 b64 write)
#pragma unroll
        for (int i = 0; i < 8; ++i) {
            int k = (bkg << 5) + (i << 2);
            const float* p = w1 + (size_t)(k0 + k) * 128 + bn;
            float a0 = p[0], a1 = p[128], a2 = p[256], a3 = p[384];
            *(uint2*)&Bs[bn * 72 + k] = make_uint2(pack2(a0, a1), pack2(a2, a3));
        }
        __syncthreads();
#pragma unroll
        for (int ks = 0; ks < 2; ++ks) {
            const bf8 a0 = *(const bf8*)&As[(w * 32 + lcol) * 72 + (ks << 5) + (quad << 3)];
            const bf8 a1 = *(const bf8*)&As[(w * 32 + 16 + lcol) * 72 + (ks << 5) + (quad << 3)];
#pragma unroll
            for (int nt = 0; nt < 8; ++nt) {
                const bf8 bb = *(const bf8*)&Bs[(nt * 16 + lcol) * 72 + (ks << 5) + (quad << 3)];
                acc[0][nt] = __builtin_amdgcn_mfma_f32_16x16x32_bf16(a0, bb, acc[0][nt], 0, 0, 0);
                acc[1][nt] = __builtin_amdgcn_mfma_f32_16x16x32_bf16(a1, bb, acc[1][nt], 0, 0, 0);
            }
        }
    }
    // epilogue: C/D layout col=lane&15, row=quad*4+reg
#pragma unroll
    for (int nt = 0; nt < 8; ++nt) {
        const int gc = (nt << 4) + lcol;
        const float bias = b1[gc];
#pragma unroll
        for (int mt = 0; mt < 2; ++mt) {
            const int rbase = row0 + w * 32 + mt * 16 + (quad << 2);
#pragma unroll
            for (int r = 0; r < 4; ++r)
                h1[(size_t)(rbase + r) * 128 + gc] = acc[mt][nt][r] + bias;
        }
    }
}

// -------- per-column sum / sumsq over h[65536,128] --------
__global__ __launch_bounds__(256) void k_bnstats(const float* __restrict__ h,
                                                 float* __restrict__ sums) {
    __shared__ float red[512];
    const int tid = threadIdx.x;
    const int gid = (blockIdx.x << 8) + tid;
    float s = 0.f, ss = 0.f;
    for (int i = gid; i < 65536 * 128; i += 512 * 256) {
        float v = h[i];
        s += v;
        ss = fmaf(v, v, ss);
    }
    red[tid] = s;
    red[256 + tid] = ss;
    __syncthreads();
    if (tid < 128) {
        atomicAdd(&sums[tid], red[tid] + red[tid + 128]);
        atomicAdd(&sums[128 + tid], red[256 + tid] + red[256 + tid + 128]);
    }
}

// -------- z = relu(bn(h1)) @ w2[128,32] + b2 (fp32 vector; cheap) --------
__global__ __launch_bounds__(256) void k_enc2(const float* __restrict__ h1,
                                              const float* __restrict__ acc,
                                              const float* __restrict__ g1,
                                              const float* __restrict__ be1,
                                              const float* __restrict__ w2,
                                              const float* __restrict__ b2,
                                              float* __restrict__ z) {
    __shared__ float Ws[128 * 32];
    __shared__ float Ar[32 * 132];
    const int tid = threadIdx.x;
    for (int i = tid; i < 4096; i += 256) Ws[i] = w2[i];
    const int k4 = tid & 31;
    float scl[4], shf[4];
#pragma unroll
    for (int j = 0; j < 4; j++) {
        int k = (k4 << 2) + j;
        float mu = acc[k] * (1.f / 65536.f);
        float var = fmaf(-mu, mu, acc[128 + k] * (1.f / 65536.f));
        float s = g1[k] * rsqrtf(var + 1e-5f);
        scl[j] = s;
        shf[j] = fmaf(-mu, s, be1[k]);
    }
    __syncthreads();
    const int row0 = blockIdx.x << 5;
#pragma unroll
    for (int i = 0; i < 4; i++) {
        int idx = (i << 8) + tid;
        int r = idx >> 5;
        float4 v = *(const float4*)(h1 + (size_t)(row0 + r) * 128 + (k4 << 2));
        v.x = fmaxf(fmaf(v.x, scl[0], shf[0]), 0.f);
        v.y = fmaxf(fmaf(v.y, scl[1], shf[1]), 0.f);
        v.z = fmaxf(fmaf(v.z, scl[2], shf[2]), 0.f);
        v.w = fmaxf(fmaf(v.w, scl[3], shf[3]), 0.f);
        *(float4*)&Ar[r * 132 + (k4 << 2)] = v;
    }
    __syncthreads();
    const int r = tid >> 3, c4 = tid & 7;
    float4 a4 = {0.f, 0.f, 0.f, 0.f};
#pragma unroll 8
    for (int k = 0; k < 128; k++) {
        const float a = Ar[r * 132 + k];
        const float4 w = *(const float4*)&Ws[k * 32 + (c4 << 2)];
        a4.x = fmaf(a, w.x, a4.x); a4.y = fmaf(a, w.y, a4.y);
        a4.z = fmaf(a, w.z, a4.z); a4.w = fmaf(a, w.w, a4.w);
    }
    const float4 bias = *(const float4*)(b2 + (c4 << 2));
    a4.x += bias.x; a4.y += bias.y; a4.z += bias.z; a4.w += bias.w;
    *(float4*)(z + (size_t)(row0 + r) * 32 + (c4 << 2)) = a4;
}

// -------- quantize (MFMA): per row argmin_k ||z-c_k||^2, sum of mins --------
// dist = zn + cn - 2 z.c ; argmin proxy = cn - 2 z.c (zn const per row).
// Block 256 thr, 128 rows; codebook staged bf16 in 2 passes of 512.
__global__ __launch_bounds__(256) void k_quant(const float* __restrict__ z,
                                               const float* __restrict__ cb,
                                               int* __restrict__ topics,
                                               float* accum) {
    __shared__ unsigned short cs[512 * 40];  // [n][k] stride 40 (80B): frag reads 2-way=free
    __shared__ unsigned short zs[128 * 32];  // [m][k] no pad (one-time frag read)
    __shared__ float cn[512], zn[128], red[256];
    const int t = threadIdx.x;
    const int w = t >> 6, lane = t & 63, quad = lane >> 4, lcol = lane & 15, part = t & 7;
    const int row0 = blockIdx.x << 7;

    // stage z rows -> bf16 + fp32 row norms
#pragma unroll
    for (int i = 0; i < 4; ++i) {
        int fidx = (i << 8) + t;
        int r = fidx >> 3, kq = (fidx & 7) << 2;
        float4 v = *(const float4*)(z + (size_t)(row0 + r) * 32 + kq);
        *(uint2*)&zs[r * 32 + kq] = make_uint2(pack2(v.x, v.y), pack2(v.z, v.w));
        float pn = v.x * v.x + v.y * v.y + v.z * v.z + v.w * v.w;
        pn += __shfl_xor(pn, 1);
        pn += __shfl_xor(pn, 2);
        pn += __shfl_xor(pn, 4);
        if (part == 0) zn[r] = pn;
    }
    __syncthreads();

    bf8 af[2];
    float4 znv[2];
#pragma unroll
    for (int mt = 0; mt < 2; ++mt) {
        af[mt] = *(const bf8*)&zs[(w * 32 + mt * 16 + lcol) * 32 + (quad << 3)];
        znv[mt] = *(const float4*)&zn[w * 32 + mt * 16 + (quad << 2)];
    }
    float best[2][4];
    int bidx[2][4];
#pragma unroll
    for (int mt = 0; mt < 2; ++mt)
#pragma unroll
        for (int r = 0; r < 4; ++r) { best[mt][r] = 3.4e38f; bidx[mt][r] = 0; }
    const f4a zero4 = {0.f, 0.f, 0.f, 0.f};

    for (int ch2 = 0; ch2 < 2; ++ch2) {
        __syncthreads();
        // stage 512 codewords -> bf16 + fp32 norms
#pragma unroll 4
        for (int i = 0; i < 16; ++i) {
            int fidx = (i << 8) + t;
            int r = fidx >> 3, kq = (fidx & 7) << 2;
            float4 v = *(const float4*)(cb + (size_t)((ch2 << 9) + r) * 32 + kq);
            *(uint2*)&cs[r * 40 + kq] = make_uint2(pack2(v.x, v.y), pack2(v.z, v.w));
            float pn = v.x * v.x + v.y * v.y + v.z * v.z + v.w * v.w;
            pn += __shfl_xor(pn, 1);
            pn += __shfl_xor(pn, 2);
            pn += __shfl_xor(pn, 4);
            if (part == 0) cn[r] = pn;
        }
        __syncthreads();
        // sweep 32 chunks of 16 codewords, software-pipelined by 1
        bf8 bb = *(const bf8*)&cs[lcol * 40 + (quad << 3)];
        float cnv = cn[lcol];
        for (int ch = 0; ch < 32; ++ch) {
            const int nn = ((ch + 1) & 31) << 4;
            const bf8 bb_n = *(const bf8*)&cs[(nn + lcol) * 40 + (quad << 3)];
            const float cn_n = cn[nn + lcol];
            const int cidx = (ch2 << 9) + (ch << 4) + lcol;
#pragma unroll
            for (int mt = 0; mt < 2; ++mt) {
                f4a a = __builtin_amdgcn_mfma_f32_16x16x32_bf16(af[mt], bb, zero4, 0, 0, 0);
#pragma unroll
                for (int r = 0; r < 4; ++r) {
                    float d = fmaf(-2.f, a[r], cnv);   // proxy: cn - 2 z.c
                    if (d < best[mt][r]) { best[mt][r] = d; bidx[mt][r] = cidx; }
                }
            }
            bb = bb_n; cnv = cn_n;
        }
    }
    // cross-lane argmin over the 16 col-classes (first-index tie-break)
#pragma unroll
    for (int off = 1; off < 16; off <<= 1) {
#pragma unroll
        for (int mt = 0; mt < 2; ++mt)
#pragma unroll
            for (int r = 0; r < 4; ++r) {
                float ob = __shfl_xor(best[mt][r], off);
                int oi = __shfl_xor(bidx[mt][r], off);
                if (ob < best[mt][r] || (ob == best[mt][r] && oi < bidx[mt][r])) {
                    best[mt][r] = ob; bidx[mt][r] = oi;
                }
            }
    }
    float lsum = 0.f;
    if (lcol == 0) {
#pragma unroll
        for (int mt = 0; mt < 2; ++mt)
#pragma unroll
            for (int r = 0; r < 4; ++r) {
                int row = row0 + w * 32 + mt * 16 + (quad << 2) + r;
                topics[row] = bidx[mt][r];
                lsum += best[mt][r] + znv[mt][r];   // add back zn for true min dist
            }
    }
    red[t] = lsum;
    __syncthreads();
    for (int s = 128; s > 0; s >>= 1) {
        if (t < s) red[t] += red[t + s];
        __syncthreads();
    }
    if (t == 0) atomicAdd(accum + 512, red[0]);
}

// -------- h2 = codebook[topics] @ dw1[32,128] + db1 (fp32 vector; cheap) --------
__global__ __launch_bounds__(256) void k_dec1(const float* __restrict__ cb,
                                              const int* __restrict__ topics,
                                              const float* __restrict__ w1,
                                              const float* __restrict__ b1,
                                              float* __restrict__ h2) {
    __shared__ float Ws[32 * 128];
    __shared__ float Qs[8 * 33];
    const int tid = threadIdx.x;
    for (int i = tid; i < 4096; i += 256) Ws[i] = w1[i];
    const int rl = tid >> 5, c4 = tid & 31;
    const float4 bias = *(const float4*)(b1 + (c4 << 2));
    const int row0 = blockIdx.x << 6;
    for (int pass = 0; pass < 8; pass++) {
        const int rbase = row0 + (pass << 3);
        __syncthreads();
        Qs[rl * 33 + c4] = cb[(size_t)topics[rbase + rl] * 32 + c4];
        __syncthreads();
        float4 a4 = {0.f, 0.f, 0.f, 0.f};
#pragma unroll
        for (int j = 0; j < 32; j++) {
            const float q = Qs[rl * 33 + j];
            const float4 w = *(const float4*)&Ws[j * 128 + (c4 << 2)];
            a4.x = fmaf(q, w.x, a4.x); a4.y = fmaf(q, w.y, a4.y);
            a4.z = fmaf(q, w.z, a4.z); a4.w = fmaf(q, w.w, a4.w);
        }
        a4.x += bias.x; a4.y += bias.y; a4.z += bias.z; a4.w += bias.w;
        *(float4*)(h2 + (size_t)(rbase + rl) * 128 + (c4 << 2)) = a4;
    }
}

// -------- dec GEMM2 (MFMA): X_ = relu(bn(h2)) @ dw2[128,512] + db2; sum((X_-X)^2) --------
// 512 thr (8 waves, 2x4), tile 128M x 256N, BK=32 (4 chunks), grid (512, 2).
__global__ __launch_bounds__(512) void k_dec2(const float* __restrict__ h2,
                                              float* acc_g,
                                              const float* __restrict__ g,
                                              const float* __restrict__ be,
                                              const float* __restrict__ w2,
                                              const float* __restrict__ b2,
                                              const float* __restrict__ X) {
    __shared__ unsigned short As[128 * 40];  // [m][k] stride 40
    __shared__ unsigned short Bs[256 * 40];  // [n][k] (w2 transposed)
    __shared__ float scl[128], shf[128];
    __shared__ float red[512];
    const int t = threadIdx.x;
    if (t < 128) {
        float mu = acc_g[256 + t] * (1.f / 65536.f);
        float var = fmaf(-mu, mu, acc_g[384 + t] * (1.f / 65536.f));
        float s = g[t] * rsqrtf(var + 1e-5f);
        scl[t] = s;
        shf[t] = fmaf(-mu, s, be[t]);
    }
    const int row0 = blockIdx.x << 7;
    const int col0 = blockIdx.y << 8;
    const int w = t >> 6, lane = t & 63, quad = lane >> 4, lcol = lane & 15;
    const int wm = w & 1, wn = w >> 1;
    f4a acc[4][4];
#pragma unroll
    for (int i = 0; i < 4; i++)
#pragma unroll
        for (int j = 0; j < 4; j++) acc[i][j] = (f4a){0.f, 0.f, 0.f, 0.f};
    __syncthreads();  // scl/shf ready

    const int bn = t & 255, bkg = t >> 8;
    for (int c = 0; c < 4; ++c) {
        const int k0 = c << 5;
        if (c) __syncthreads();
        // A: 128 rows x 32 k, BN+ReLU fused, fp32->bf16
#pragma unroll
        for (int i = 0; i < 2; ++i) {
            int fidx = (i << 9) + t;
            int r = fidx >> 3, kq = (fidx & 7) << 2;
            float4 v = *(const float4*)(h2 + (size_t)(row0 + r) * 128 + k0 + kq);
            v.x = fmaxf(fmaf(v.x, scl[k0 + kq + 0], shf[k0 + kq + 0]), 0.f);
            v.y = fmaxf(fmaf(v.y, scl[k0 + kq + 1], shf[k0 + kq + 1]), 0.f);
            v.z = fmaxf(fmaf(v.z, scl[k0 + kq + 2], shf[k0 + kq + 2]), 0.f);
            v.w = fmaxf(fmaf(v.w, scl[k0 + kq + 3], shf[k0 + kq + 3]), 0.f);
            *(uint2*)&As[r * 40 + kq] = make_uint2(pack2(v.x, v.y), pack2(v.z, v.w));
        }
        // B: w2 chunk [32k][256n] -> Bs[n][k]
#pragma unroll
        for (int i = 0; i < 4; ++i) {
            int k = (bkg << 4) + (i << 2);
            const float* p = w2 + (size_t)(k0 + k) * 512 + col0 + bn;
            float a0 = p[0], a1 = p[512], a2 = p[1024], a3 = p[1536];
            *(uint2*)&Bs[bn * 40 + k] = make_uint2(pack2(a0, a1), pack2(a2, a3));
        }
        __syncthreads();
        bf8 af[4];
#pragma unroll
        for (int mt = 0; mt < 4; ++mt)
            af[mt] = *(const bf8*)&As[(wm * 64 + mt * 16 + lcol) * 40 + (quad << 3)];
#pragma unroll
        for (int nt = 0; nt < 4; ++nt) {
            const bf8 bb = *(const bf8*)&Bs[(wn * 64 + nt * 16 + lcol) * 40 + (quad << 3)];
#pragma unroll
            for (int mt = 0; mt < 4; ++mt)
                acc[mt][nt] = __builtin_amdgcn_mfma_f32_16x16x32_bf16(af[mt], bb, acc[mt][nt], 0, 0, 0);
        }
    }
    // epilogue: bias, diff vs X, block-reduce
    float lsum = 0.f;
#pragma unroll
    for (int nt = 0; nt < 4; ++nt) {
        const int gc = col0 + wn * 64 + nt * 16 + lcol;
        const float bias = b2[gc];
#pragma unroll
        for (int mt = 0; mt < 4; ++mt) {
            const int rbase = row0 + wm * 64 + mt * 16 + (quad << 2);
#pragma unroll
            for (int r = 0; r < 4; ++r) {
                float val = acc[mt][nt][r] + bias;
                float d = val - X[(size_t)(rbase + r) * 512 + gc];
                lsum = fmaf(d, d, lsum);
            }
        }
    }
    red[t] = lsum;
    __syncthreads();
    for (int s = 256; s > 0; s >>= 1) {
        if (t < s) red[t] += red[t + s];
        __syncthreads();
    }
    if (t == 0) atomicAdd(acc_g + 513, red[0]);
}

__global__ void k_final(const float* __restrict__ acc, float* __restrict__ out) {
    if (threadIdx.x == 0) out[0] = 2.f * acc[512] + sqrtf(acc[513]);
}

extern "C" void kernel_launch(void* const* d_in, const int* in_sizes, int n_in,
                              void* d_out, int out_size, void* d_ws, size_t ws_size,
                              hipStream_t stream) {
    const float* X       = (const float*)d_in[0];
    const float* enc_w1  = (const float*)d_in[1];
    const float* enc_b1  = (const float*)d_in[2];
    const float* enc_g1  = (const float*)d_in[3];
    const float* enc_be1 = (const float*)d_in[4];
    const float* enc_w2  = (const float*)d_in[5];
    const float* enc_b2  = (const float*)d_in[6];
    const float* dec_w1  = (const float*)d_in[7];
    const float* dec_b1  = (const float*)d_in[8];
    const float* dec_g1  = (const float*)d_in[9];
    const float* dec_be1 = (const float*)d_in[10];
    const float* dec_w2  = (const float*)d_in[11];
    const float* dec_b2  = (const float*)d_in[12];
    const float* cb      = (const float*)d_in[13];
    float* out = (float*)d_out;

    float* acc    = (float*)d_ws;               // 1024 floats
    int*   topics = (int*)(acc + 1024);         // 65536 ints
    float* z      = (float*)(topics + 65536);   // 65536*32
    float* h      = z + (size_t)65536 * 32;     // 65536*128 (h1, then reused as h2)

    k_init<<<4, 256, 0, stream>>>(acc);
    k_enc1<<<512, 256, 0, stream>>>(X, enc_w1, enc_b1, h);
    k_bnstats<<<512, 256, 0, stream>>>(h, acc);
    k_enc2<<<2048, 256, 0, stream>>>(h, acc, enc_g1, enc_be1, enc_w2, enc_b2, z);
    k_quant<<<512, 256, 0, stream>>>(z, cb, topics, acc);
    k_dec1<<<1024, 256, 0, stream>>>(cb, topics, dec_w1, dec_b1, h);
    k_bnstats<<<512, 256, 0, stream>>>(h, acc + 256);
    k_dec2<<<dim3(512, 2), 512, 0, stream>>>(h, acc, dec_g1, dec_be1, dec_w2, dec_b2, X);
    k_final<<<1, 64, 0, stream>>>(acc, out);
}

// Round 3
// 328.326 us; speedup vs baseline: 2.2192x; 1.2405x over previous
//
#include <hip/hip_runtime.h>
#include <math.h>

// VQ-AE forward, fully fused bf16-MFMA version (3 worker kernels).
// N=65536, Din=512, H=128, D=32, K=1024. Output: single f32 scalar.
// ws: acc[1024] f32 | h1b[65536*128] bf16 | h2b[65536*128] bf16
// acc: [0..127] sum1, [128..255] sumsq1, [256..383] sum2, [384..511] sumsq2,
//      [512] min-dist sum, [513] sq-diff sum

typedef __attribute__((ext_vector_type(8))) short bf8;
typedef __attribute__((ext_vector_type(4))) float f4a;

__device__ __forceinline__ unsigned short f2bf(float f) {
    unsigned u = __float_as_uint(f);
    u += 0x7fffu + ((u >> 16) & 1u);   // RNE
    return (unsigned short)(u >> 16);
}
__device__ __forceinline__ unsigned pack2(float a, float b) {
    return (unsigned)f2bf(a) | ((unsigned)f2bf(b) << 16);
}
__device__ __forceinline__ void unpack2(unsigned p, float& lo, float& hi) {
    lo = __uint_as_float(p << 16);
    hi = __uint_as_float(p & 0xffff0000u);
}

__global__ __launch_bounds__(256) void k_init(float* acc) {
    acc[(blockIdx.x << 8) + threadIdx.x] = 0.f;
}

// ======== K1: h1b = bf16(X@w1 + b1), + column sum/sumsq -> acc[0..255] ========
// 512 blocks x 256 thr; tile 128M x 128N, BK=64 (8 chunks).
__global__ __launch_bounds__(256) void k_enc1(const float* __restrict__ X,
                                              const float* __restrict__ w1,
                                              const float* __restrict__ b1,
                                              unsigned short* __restrict__ h1b,
                                              float* __restrict__ acc_g) {
    __shared__ unsigned short As[128 * 72];
    __shared__ unsigned short Bs[128 * 72];
    __shared__ float sred[2 * 4 * 128];   // [stat][wave][col]
    const int t = threadIdx.x;
    const int row0 = blockIdx.x << 7;
    const int w = t >> 6, lane = t & 63, quad = lane >> 4, lcol = lane & 15;
    f4a acc[2][8];
#pragma unroll
    for (int i = 0; i < 2; i++)
#pragma unroll
        for (int j = 0; j < 8; j++) acc[i][j] = (f4a){0.f, 0.f, 0.f, 0.f};

    const int bn = t & 127, bkg = t >> 7;
    for (int c = 0; c < 8; ++c) {
        const int k0 = c << 6;
        __syncthreads();
#pragma unroll
        for (int i = 0; i < 8; ++i) {
            int fidx = (i << 8) + t;
            int r = fidx >> 4, kq = (fidx & 15) << 2;
            float4 v = *(const float4*)(X + (size_t)(row0 + r) * 512 + k0 + kq);
            *(uint2*)&As[r * 72 + kq] = make_uint2(pack2(v.x, v.y), pack2(v.z, v.w));
        }
#pragma unroll
        for (int i = 0; i < 8; ++i) {
            int k = (bkg << 5) + (i << 2);
            const float* p = w1 + (size_t)(k0 + k) * 128 + bn;
            float a0 = p[0], a1 = p[128], a2 = p[256], a3 = p[384];
            *(uint2*)&Bs[bn * 72 + k] = make_uint2(pack2(a0, a1), pack2(a2, a3));
        }
        __syncthreads();
#pragma unroll
        for (int ks = 0; ks < 2; ++ks) {
            const bf8 a0 = *(const bf8*)&As[(w * 32 + lcol) * 72 + (ks << 5) + (quad << 3)];
            const bf8 a1 = *(const bf8*)&As[(w * 32 + 16 + lcol) * 72 + (ks << 5) + (quad << 3)];
#pragma unroll
            for (int nt = 0; nt < 8; ++nt) {
                const bf8 bb = *(const bf8*)&Bs[(nt * 16 + lcol) * 72 + (ks << 5) + (quad << 3)];
                acc[0][nt] = __builtin_amdgcn_mfma_f32_16x16x32_bf16(a0, bb, acc[0][nt], 0, 0, 0);
                acc[1][nt] = __builtin_amdgcn_mfma_f32_16x16x32_bf16(a1, bb, acc[1][nt], 0, 0, 0);
            }
        }
    }
    // epilogue: store bf16 + per-column stats (C/D: col=lane&15, row=quad*4+r)
#pragma unroll
    for (int nt = 0; nt < 8; ++nt) {
        const int gc = (nt << 4) + lcol;
        const float bias = b1[gc];
        float s = 0.f, ss = 0.f;
#pragma unroll
        for (int mt = 0; mt < 2; ++mt) {
            const int rbase = row0 + w * 32 + mt * 16 + (quad << 2);
#pragma unroll
            for (int r = 0; r < 4; ++r) {
                float v = acc[mt][nt][r] + bias;
                h1b[(size_t)(rbase + r) * 128 + gc] = f2bf(v);
                s += v;
                ss = fmaf(v, v, ss);
            }
        }
        s += __shfl_xor(s, 16);  s += __shfl_xor(s, 32);
        ss += __shfl_xor(ss, 16); ss += __shfl_xor(ss, 32);
        if (quad == 0) { sred[w * 128 + gc] = s; sred[512 + w * 128 + gc] = ss; }
    }
    __syncthreads();
    if (t < 128) {
        atomicAdd(&acc_g[t], sred[t] + sred[128 + t] + sred[256 + t] + sred[384 + t]);
        atomicAdd(&acc_g[128 + t], sred[512 + t] + sred[640 + t] + sred[768 + t] + sred[896 + t]);
    }
}

// ======== K2: fused enc2 + quantize + dec1 + stats2 ========
// 512 blocks x 256 thr, 128 rows/block.
__global__ __launch_bounds__(256) void k_mid(const unsigned short* __restrict__ h1b,
                                             const float* __restrict__ w2e,
                                             const float* __restrict__ b2e,
                                             const float* __restrict__ g1,
                                             const float* __restrict__ be1,
                                             const float* __restrict__ cb,
                                             const float* __restrict__ w1d,
                                             const float* __restrict__ b1d,
                                             unsigned short* __restrict__ h2b,
                                             float* __restrict__ acc_g) {
    // LDS pool (49152 B):
    //  [0,20480)      cs   (256cw x 40 ushort)  -- overlays As2 [0,18432)
    //  [0,4096)       sstat (2x4x128 f32)       -- used only after sweeps done
    //  [20480,25088)  Bs2  (w2^T, 32n x 72k ushort... 32*72*2)
    //  [25088,35328)  Bs3  (w1d^T, 128n x 40 ushort)
    //  [35328,45568)  zs   (128m x 40 ushort)   -- later reused as gathered-codeword A-tile
    //  [45568,46592)  cn   (256 f32)
    //  [46592,47616)  scl/shf (128+128 f32)
    //  [47616,48640)  red  (256 f32)
    //  [48640,49152)  topicsL (128 i32)
    __shared__ __align__(16) char pool[49152];
    unsigned short* As2 = (unsigned short*)pool;          // [m][k] stride 72
    unsigned short* cs  = (unsigned short*)pool;          // [n][k] stride 40
    float*          sstat = (float*)pool;
    unsigned short* Bs2 = (unsigned short*)(pool + 20480);
    unsigned short* Bs3 = (unsigned short*)(pool + 25088);
    unsigned short* zs  = (unsigned short*)(pool + 35328);
    float* cn  = (float*)(pool + 45568);
    float* scl = (float*)(pool + 46592);
    float* shf = (float*)(pool + 47104);
    float* red = (float*)(pool + 47616);
    int* topicsL = (int*)(pool + 48640);

    const int t = threadIdx.x;
    const int w = t >> 6, lane = t & 63, quad = lane >> 4, lcol = lane & 15;
    const int row0 = blockIdx.x << 7;

    // --- BN params (enc) ---
    if (t < 128) {
        float mu = acc_g[t] * (1.f / 65536.f);
        float var = fmaf(-mu, mu, acc_g[128 + t] * (1.f / 65536.f));
        float s = g1[t] * rsqrtf(var + 1e-5f);
        scl[t] = s;
        shf[t] = fmaf(-mu, s, be1[t]);
    }
    // --- stage Bs3 = w1d^T (w1d: [32][128]) ---
#pragma unroll
    for (int i = 0; i < 16; ++i) {
        int idx = (i << 8) + t;
        int n = idx & 127, k = idx >> 7;
        Bs3[n * 40 + k] = f2bf(w1d[k * 128 + n]);
    }
    // --- stage Bs2 = w2e^T (w2e: [128][32]) ---
#pragma unroll
    for (int i = 0; i < 16; ++i) {
        int idx = (i << 8) + t;
        int n = idx & 31, k = idx >> 5;
        Bs2[n * 72 + k] = f2bf(w2e[k * 32 + n]);
    }
    __syncthreads();
    // --- stage As2 = bn_relu(h1b tile) [128m][128k] ---
#pragma unroll
    for (int i = 0; i < 8; ++i) {
        int fidx = (i << 8) + t;
        int r = fidx >> 4, kq = (fidx & 15) << 3;
        uint4 raw = *(const uint4*)(h1b + (size_t)(row0 + r) * 128 + kq);
        unsigned pv[4] = {raw.x, raw.y, raw.z, raw.w};
        unsigned ov[4];
#pragma unroll
        for (int j = 0; j < 4; ++j) {
            float lo, hi;
            unpack2(pv[j], lo, hi);
            int k = kq + 2 * j;
            lo = fmaxf(fmaf(lo, scl[k], shf[k]), 0.f);
            hi = fmaxf(fmaf(hi, scl[k + 1], shf[k + 1]), 0.f);
            ov[j] = pack2(lo, hi);
        }
        *(uint4*)&As2[r * 72 + kq] = make_uint4(ov[0], ov[1], ov[2], ov[3]);
    }
    __syncthreads();
    // --- z-GEMM: 32 rows/wave x 32 cols, K=128 ---
    f4a zacc[2][2];
#pragma unroll
    for (int i = 0; i < 2; ++i)
#pragma unroll
        for (int j = 0; j < 2; ++j) zacc[i][j] = (f4a){0.f, 0.f, 0.f, 0.f};
#pragma unroll
    for (int kc = 0; kc < 4; ++kc) {
        const bf8 a0 = *(const bf8*)&As2[(w * 32 + lcol) * 72 + (kc << 5) + (quad << 3)];
        const bf8 a1 = *(const bf8*)&As2[(w * 32 + 16 + lcol) * 72 + (kc << 5) + (quad << 3)];
        const bf8 b0 = *(const bf8*)&Bs2[lcol * 72 + (kc << 5) + (quad << 3)];
        const bf8 b1v = *(const bf8*)&Bs2[(16 + lcol) * 72 + (kc << 5) + (quad << 3)];
        zacc[0][0] = __builtin_amdgcn_mfma_f32_16x16x32_bf16(a0, b0, zacc[0][0], 0, 0, 0);
        zacc[0][1] = __builtin_amdgcn_mfma_f32_16x16x32_bf16(a0, b1v, zacc[0][1], 0, 0, 0);
        zacc[1][0] = __builtin_amdgcn_mfma_f32_16x16x32_bf16(a1, b0, zacc[1][0], 0, 0, 0);
        zacc[1][1] = __builtin_amdgcn_mfma_f32_16x16x32_bf16(a1, b1v, zacc[1][1], 0, 0, 0);
    }
    // --- bias, z-norms (fp32), zs write (bf16, A-layout) ---
    const float b2lo = b2e[lcol], b2hi = b2e[16 + lcol];
    float znv[2][4];
#pragma unroll
    for (int mt = 0; mt < 2; ++mt) {
#pragma unroll
        for (int r = 0; r < 4; ++r) {
            float v0 = zacc[mt][0][r] + b2lo;
            float v1 = zacc[mt][1][r] + b2hi;
            int row = w * 32 + mt * 16 + (quad << 2) + r;
            zs[row * 40 + lcol] = f2bf(v0);
            zs[row * 40 + 16 + lcol] = f2bf(v1);
            float s = v0 * v0 + v1 * v1;
            s += __shfl_xor(s, 1); s += __shfl_xor(s, 2);
            s += __shfl_xor(s, 4); s += __shfl_xor(s, 8);
            znv[mt][r] = s;  // full row norm, all 16 lanes of quad
        }
    }
    __syncthreads();
    // --- quant sweep: A-frags from zs, codebook in 4 passes of 256 ---
    bf8 af[2];
    af[0] = *(const bf8*)&zs[(w * 32 + lcol) * 40 + (quad << 3)];
    af[1] = *(const bf8*)&zs[(w * 32 + 16 + lcol) * 40 + (quad << 3)];
    float best[2][4];
    int bidx[2][4];
#pragma unroll
    for (int mt = 0; mt < 2; ++mt)
#pragma unroll
        for (int r = 0; r < 4; ++r) { best[mt][r] = 3.4e38f; bidx[mt][r] = 0; }
    const f4a zero4 = {0.f, 0.f, 0.f, 0.f};

    for (int cp = 0; cp < 4; ++cp) {
        __syncthreads();
#pragma unroll 4
        for (int i = 0; i < 8; ++i) {
            int fidx = (i << 8) + t;
            int r = fidx >> 3, kq = (fidx & 7) << 2;
            float4 v = *(const float4*)(cb + (size_t)((cp << 8) + r) * 32 + kq);
            *(uint2*)&cs[r * 40 + kq] = make_uint2(pack2(v.x, v.y), pack2(v.z, v.w));
            float pn = v.x * v.x + v.y * v.y + v.z * v.z + v.w * v.w;
            pn += __shfl_xor(pn, 1);
            pn += __shfl_xor(pn, 2);
            pn += __shfl_xor(pn, 4);
            if ((t & 7) == 0) cn[r] = pn;
        }
        __syncthreads();
        bf8 bb = *(const bf8*)&cs[lcol * 40 + (quad << 3)];
        float cnv = cn[lcol];
        for (int ch = 0; ch < 16; ++ch) {
            const int nn = ((ch + 1) & 15) << 4;
            const bf8 bb_n = *(const bf8*)&cs[(nn + lcol) * 40 + (quad << 3)];
            const float cn_n = cn[nn + lcol];
            const int cidx = (cp << 8) + (ch << 4) + lcol;
#pragma unroll
            for (int mt = 0; mt < 2; ++mt) {
                f4a a = __builtin_amdgcn_mfma_f32_16x16x32_bf16(af[mt], bb, zero4, 0, 0, 0);
#pragma unroll
                for (int r = 0; r < 4; ++r) {
                    float d = fmaf(-2.f, a[r], cnv);   // proxy: cn - 2 z.c
                    if (d < best[mt][r]) { best[mt][r] = d; bidx[mt][r] = cidx; }
                }
            }
            bb = bb_n; cnv = cn_n;
        }
    }
    // --- cross-lane argmin (first-index tie-break), topics + z_loss ---
#pragma unroll
    for (int off = 1; off < 16; off <<= 1) {
#pragma unroll
        for (int mt = 0; mt < 2; ++mt)
#pragma unroll
            for (int r = 0; r < 4; ++r) {
                float ob = __shfl_xor(best[mt][r], off);
                int oi = __shfl_xor(bidx[mt][r], off);
                if (ob < best[mt][r] || (ob == best[mt][r] && oi < bidx[mt][r])) {
                    best[mt][r] = ob; bidx[mt][r] = oi;
                }
            }
    }
    float lsum = 0.f;
    if (lcol == 0) {
#pragma unroll
        for (int mt = 0; mt < 2; ++mt)
#pragma unroll
            for (int r = 0; r < 4; ++r) {
                int row = w * 32 + mt * 16 + (quad << 2) + r;
                topicsL[row] = bidx[mt][r];
                lsum += best[mt][r] + znv[mt][r];
            }
    }
    red[t] = lsum;
    __syncthreads();
    for (int s = 128; s > 0; s >>= 1) {
        if (t < s) red[t] += red[t + s];
        __syncthreads();
    }
    if (t == 0) atomicAdd(acc_g + 512, red[0]);
    // (reduce loop ends with __syncthreads: all waves past sweeps here)

    // --- gather selected codewords into zs region (As3) ---
#pragma unroll
    for (int i = 0; i < 4; ++i) {
        int fidx = (i << 8) + t;
        int r = fidx >> 3, kq = (fidx & 7) << 2;
        float4 v = *(const float4*)(cb + (size_t)topicsL[r] * 32 + kq);
        *(uint2*)&zs[r * 40 + kq] = make_uint2(pack2(v.x, v.y), pack2(v.z, v.w));
    }
    __syncthreads();
    // --- dec1 GEMM: h2 = As3[128x32] @ Bs3^T + b1d, K=32 ---
    f4a dacc[2][8];
#pragma unroll
    for (int i = 0; i < 2; ++i)
#pragma unroll
        for (int j = 0; j < 8; ++j) dacc[i][j] = (f4a){0.f, 0.f, 0.f, 0.f};
    const bf8 da0 = *(const bf8*)&zs[(w * 32 + lcol) * 40 + (quad << 3)];
    const bf8 da1 = *(const bf8*)&zs[(w * 32 + 16 + lcol) * 40 + (quad << 3)];
#pragma unroll
    for (int nt = 0; nt < 8; ++nt) {
        const bf8 bb = *(const bf8*)&Bs3[(nt * 16 + lcol) * 40 + (quad << 3)];
        dacc[0][nt] = __builtin_amdgcn_mfma_f32_16x16x32_bf16(da0, bb, dacc[0][nt], 0, 0, 0);
        dacc[1][nt] = __builtin_amdgcn_mfma_f32_16x16x32_bf16(da1, bb, dacc[1][nt], 0, 0, 0);
    }
    __syncthreads();   // zs/Bs3 reads done; sstat (aliases pool base) written next
    // --- epilogue: h2b store + stats2 ---
#pragma unroll
    for (int nt = 0; nt < 8; ++nt) {
        const int gc = (nt << 4) + lcol;
        const float bias = b1d[gc];
        float s = 0.f, ss = 0.f;
#pragma unroll
        for (int mt = 0; mt < 2; ++mt) {
            const int rbase = row0 + w * 32 + mt * 16 + (quad << 2);
#pragma unroll
            for (int r = 0; r < 4; ++r) {
                float v = dacc[mt][nt][r] + bias;
                h2b[(size_t)(rbase + r) * 128 + gc] = f2bf(v);
                s += v;
                ss = fmaf(v, v, ss);
            }
        }
        s += __shfl_xor(s, 16);  s += __shfl_xor(s, 32);
        ss += __shfl_xor(ss, 16); ss += __shfl_xor(ss, 32);
        if (quad == 0) { sstat[w * 128 + gc] = s; sstat[512 + w * 128 + gc] = ss; }
    }
    __syncthreads();
    if (t < 128) {
        atomicAdd(&acc_g[256 + t], sstat[t] + sstat[128 + t] + sstat[256 + t] + sstat[384 + t]);
        atomicAdd(&acc_g[384 + t], sstat[512 + t] + sstat[640 + t] + sstat[768 + t] + sstat[896 + t]);
    }
}

// ======== K3: X_ = relu(bn(h2b))@dw2 + db2 ; accumulate sum((X_-X)^2) ========
// 512 thr (8 waves, 2x4), tile 128M x 256N, BK=32 (4 chunks), grid (512, 2).
__global__ __launch_bounds__(512) void k_dec2(const unsigned short* __restrict__ h2b,
                                              float* acc_g,
                                              const float* __restrict__ g,
                                              const float* __restrict__ be,
                                              const float* __restrict__ w2,
                                              const float* __restrict__ b2,
                                              const float* __restrict__ X) {
    __shared__ unsigned short As[128 * 40];
    __shared__ unsigned short Bs[256 * 40];
    __shared__ float scl[128], shf[128];
    __shared__ float red[512];
    const int t = threadIdx.x;
    if (t < 128) {
        float mu = acc_g[256 + t] * (1.f / 65536.f);
        float var = fmaf(-mu, mu, acc_g[384 + t] * (1.f / 65536.f));
        float s = g[t] * rsqrtf(var + 1e-5f);
        scl[t] = s;
        shf[t] = fmaf(-mu, s, be[t]);
    }
    const int row0 = blockIdx.x << 7;
    const int col0 = blockIdx.y << 8;
    const int w = t >> 6, lane = t & 63, quad = lane >> 4, lcol = lane & 15;
    const int wm = w & 1, wn = w >> 1;
    f4a acc[4][4];
#pragma unroll
    for (int i = 0; i < 4; i++)
#pragma unroll
        for (int j = 0; j < 4; j++) acc[i][j] = (f4a){0.f, 0.f, 0.f, 0.f};
    __syncthreads();

    const int bn = t & 255, bkg = t >> 8;
    const int ar = t >> 2, akq = (t & 3) << 3;
    for (int c = 0; c < 4; ++c) {
        const int k0 = c << 5;
        if (c) __syncthreads();
        // A: bf16 h2 tile, BN+ReLU fused
        {
            uint4 raw = *(const uint4*)(h2b + (size_t)(row0 + ar) * 128 + k0 + akq);
            unsigned pv[4] = {raw.x, raw.y, raw.z, raw.w};
            unsigned ov[4];
#pragma unroll
            for (int j = 0; j < 4; ++j) {
                float lo, hi;
                unpack2(pv[j], lo, hi);
                int k = k0 + akq + 2 * j;
                lo = fmaxf(fmaf(lo, scl[k], shf[k]), 0.f);
                hi = fmaxf(fmaf(hi, scl[k + 1], shf[k + 1]), 0.f);
                ov[j] = pack2(lo, hi);
            }
            *(uint4*)&As[ar * 40 + akq] = make_uint4(ov[0], ov[1], ov[2], ov[3]);
        }
        // B: w2 chunk [32k][256n] -> Bs[n][k]
#pragma unroll
        for (int i = 0; i < 4; ++i) {
            int k = (bkg << 4) + (i << 2);
            const float* p = w2 + (size_t)(k0 + k) * 512 + col0 + bn;
            float a0 = p[0], a1 = p[512], a2 = p[1024], a3 = p[1536];
            *(uint2*)&Bs[bn * 40 + k] = make_uint2(pack2(a0, a1), pack2(a2, a3));
        }
        __syncthreads();
        bf8 af[4];
#pragma unroll
        for (int mt = 0; mt < 4; ++mt)
            af[mt] = *(const bf8*)&As[(wm * 64 + mt * 16 + lcol) * 40 + (quad << 3)];
#pragma unroll
        for (int nt = 0; nt < 4; ++nt) {
            const bf8 bb = *(const bf8*)&Bs[(wn * 64 + nt * 16 + lcol) * 40 + (quad << 3)];
#pragma unroll
            for (int mt = 0; mt < 4; ++mt)
                acc[mt][nt] = __builtin_amdgcn_mfma_f32_16x16x32_bf16(af[mt], bb, acc[mt][nt], 0, 0, 0);
        }
    }
    // epilogue: bias, diff vs X, block-reduce
    float lsum = 0.f;
#pragma unroll
    for (int nt = 0; nt < 4; ++nt) {
        const int gc = col0 + wn * 64 + nt * 16 + lcol;
        const float bias = b2[gc];
#pragma unroll
        for (int mt = 0; mt < 4; ++mt) {
            const int rbase = row0 + wm * 64 + mt * 16 + (quad << 2);
#pragma unroll
            for (int r = 0; r < 4; ++r) {
                float val = acc[mt][nt][r] + bias;
                float d = val - X[(size_t)(rbase + r) * 512 + gc];
                lsum = fmaf(d, d, lsum);
            }
        }
    }
    red[t] = lsum;
    __syncthreads();
    for (int s = 256; s > 0; s >>= 1) {
        if (t < s) red[t] += red[t + s];
        __syncthreads();
    }
    if (t == 0) atomicAdd(acc_g + 513, red[0]);
}

__global__ void k_final(const float* __restrict__ acc, float* __restrict__ out) {
    if (threadIdx.x == 0) out[0] = 2.f * acc[512] + sqrtf(acc[513]);
}

extern "C" void kernel_launch(void* const* d_in, const int* in_sizes, int n_in,
                              void* d_out, int out_size, void* d_ws, size_t ws_size,
                              hipStream_t stream) {
    const float* X       = (const float*)d_in[0];
    const float* enc_w1  = (const float*)d_in[1];
    const float* enc_b1  = (const float*)d_in[2];
    const float* enc_g1  = (const float*)d_in[3];
    const float* enc_be1 = (const float*)d_in[4];
    const float* enc_w2  = (const float*)d_in[5];
    const float* enc_b2  = (const float*)d_in[6];
    const float* dec_w1  = (const float*)d_in[7];
    const float* dec_b1  = (const float*)d_in[8];
    const float* dec_g1  = (const float*)d_in[9];
    const float* dec_be1 = (const float*)d_in[10];
    const float* dec_w2  = (const float*)d_in[11];
    const float* dec_b2  = (const float*)d_in[12];
    const float* cb      = (const float*)d_in[13];
    float* out = (float*)d_out;

    float* acc = (float*)d_ws;                               // 1024 f32
    unsigned short* h1b = (unsigned short*)(acc + 1024);     // 65536*128 bf16
    unsigned short* h2b = h1b + (size_t)65536 * 128;         // 65536*128 bf16

    k_init<<<4, 256, 0, stream>>>(acc);
    k_enc1<<<512, 256, 0, stream>>>(X, enc_w1, enc_b1, h1b, acc);
    k_mid<<<512, 256, 0, stream>>>(h1b, enc_w2, enc_b2, enc_g1, enc_be1,
                                   cb, dec_w1, dec_b1, h2b, acc);
    k_dec2<<<dim3(512, 2), 512, 0, stream>>>(h2b, acc, dec_g1, dec_be1, dec_w2, dec_b2, X);
    k_final<<<1, 64, 0, stream>>>(acc, out);
}

// Round 4
// 319.028 us; speedup vs baseline: 2.2839x; 1.0291x over previous
//
#include <hip/hip_runtime.h>
#include <math.h>

// VQ-AE forward, fused bf16-MFMA version + fp32 distance recompute.
// N=65536, Din=512, H=128, D=32, K=1024. Output: single f32 scalar.
// ws: acc[1024] f32 | cbb[1024*32] bf16 | cn_g[1024] f32 | h1b[65536*128] bf16 | h2b[...] bf16
// acc: [0..127] sum1, [128..255] sumsq1, [256..383] sum2, [384..511] sumsq2,
//      [512] min-dist sum, [513] sq-diff sum

typedef __attribute__((ext_vector_type(8))) short bf8;
typedef __attribute__((ext_vector_type(4))) float f4a;

__device__ __forceinline__ unsigned short f2bf(float f) {
    unsigned u = __float_as_uint(f);
    u += 0x7fffu + ((u >> 16) & 1u);   // RNE
    return (unsigned short)(u >> 16);
}
__device__ __forceinline__ unsigned pack2(float a, float b) {
    return (unsigned)f2bf(a) | ((unsigned)f2bf(b) << 16);
}
__device__ __forceinline__ void unpack2(unsigned p, float& lo, float& hi) {
    lo = __uint_as_float(p << 16);
    hi = __uint_as_float(p & 0xffff0000u);
}

// ======== K0: zero acc + codebook -> bf16 + fp32 norms ========
__global__ __launch_bounds__(256) void k_prep(const float* __restrict__ cb,
                                              float* __restrict__ acc,
                                              unsigned short* __restrict__ cbb,
                                              float* __restrict__ cn_g) {
    const int b = blockIdx.x, t = threadIdx.x;
    if (b < 4) {
        const int cw = (b << 8) + t;
        const float* p = cb + (size_t)cw * 32;
        unsigned pk[8];
        float n = 0.f;
#pragma unroll
        for (int i = 0; i < 8; ++i) {
            float4 v = *(const float4*)(p + (i << 2));
            n = fmaf(v.x, v.x, n); n = fmaf(v.y, v.y, n);
            n = fmaf(v.z, v.z, n); n = fmaf(v.w, v.w, n);
            pk[i] = pack2(v.x, v.y);
            ++i;
            // (unrolled pair below)
            --i;
        }
        // repack properly: 32 floats -> 16 uint (2 bf16 each)
        unsigned out[16];
#pragma unroll
        for (int i = 0; i < 8; ++i) {
            float4 v = *(const float4*)(p + (i << 2));
            out[2 * i]     = pack2(v.x, v.y);
            out[2 * i + 1] = pack2(v.z, v.w);
        }
        (void)pk;
#pragma unroll
        for (int i = 0; i < 4; ++i)
            *(uint4*)(cbb + (size_t)cw * 32 + (i << 3)) =
                make_uint4(out[4 * i], out[4 * i + 1], out[4 * i + 2], out[4 * i + 3]);
        cn_g[cw] = n;
    } else {
        for (int i = t; i < 1024; i += 256) acc[i] = 0.f;
    }
}

// ======== K1: h1b = bf16(X@w1 + b1), + column sum/sumsq -> acc[0..255] ========
__global__ __launch_bounds__(256) void k_enc1(const float* __restrict__ X,
                                              const float* __restrict__ w1,
                                              const float* __restrict__ b1,
                                              unsigned short* __restrict__ h1b,
                                              float* __restrict__ acc_g) {
    __shared__ unsigned short As[128 * 72];
    __shared__ unsigned short Bs[128 * 72];
    __shared__ float sred[2 * 4 * 128];   // [stat][wave][col]
    const int t = threadIdx.x;
    const int row0 = blockIdx.x << 7;
    const int w = t >> 6, lane = t & 63, quad = lane >> 4, lcol = lane & 15;
    f4a acc[2][8];
#pragma unroll
    for (int i = 0; i < 2; i++)
#pragma unroll
        for (int j = 0; j < 8; j++) acc[i][j] = (f4a){0.f, 0.f, 0.f, 0.f};

    const int bn = t & 127, bkg = t >> 7;
    for (int c = 0; c < 8; ++c) {
        const int k0 = c << 6;
        __syncthreads();
#pragma unroll
        for (int i = 0; i < 8; ++i) {
            int fidx = (i << 8) + t;
            int r = fidx >> 4, kq = (fidx & 15) << 2;
            float4 v = *(const float4*)(X + (size_t)(row0 + r) * 512 + k0 + kq);
            *(uint2*)&As[r * 72 + kq] = make_uint2(pack2(v.x, v.y), pack2(v.z, v.w));
        }
#pragma unroll
        for (int i = 0; i < 8; ++i) {
            int k = (bkg << 5) + (i << 2);
            const float* p = w1 + (size_t)(k0 + k) * 128 + bn;
            float a0 = p[0], a1 = p[128], a2 = p[256], a3 = p[384];
            *(uint2*)&Bs[bn * 72 + k] = make_uint2(pack2(a0, a1), pack2(a2, a3));
        }
        __syncthreads();
#pragma unroll
        for (int ks = 0; ks < 2; ++ks) {
            const bf8 a0 = *(const bf8*)&As[(w * 32 + lcol) * 72 + (ks << 5) + (quad << 3)];
            const bf8 a1 = *(const bf8*)&As[(w * 32 + 16 + lcol) * 72 + (ks << 5) + (quad << 3)];
#pragma unroll
            for (int nt = 0; nt < 8; ++nt) {
                const bf8 bb = *(const bf8*)&Bs[(nt * 16 + lcol) * 72 + (ks << 5) + (quad << 3)];
                acc[0][nt] = __builtin_amdgcn_mfma_f32_16x16x32_bf16(a0, bb, acc[0][nt], 0, 0, 0);
                acc[1][nt] = __builtin_amdgcn_mfma_f32_16x16x32_bf16(a1, bb, acc[1][nt], 0, 0, 0);
            }
        }
    }
#pragma unroll
    for (int nt = 0; nt < 8; ++nt) {
        const int gc = (nt << 4) + lcol;
        const float bias = b1[gc];
        float s = 0.f, ss = 0.f;
#pragma unroll
        for (int mt = 0; mt < 2; ++mt) {
            const int rbase = row0 + w * 32 + mt * 16 + (quad << 2);
#pragma unroll
            for (int r = 0; r < 4; ++r) {
                float v = acc[mt][nt][r] + bias;
                h1b[(size_t)(rbase + r) * 128 + gc] = f2bf(v);
                s += v;
                ss = fmaf(v, v, ss);
            }
        }
        s += __shfl_xor(s, 16);  s += __shfl_xor(s, 32);
        ss += __shfl_xor(ss, 16); ss += __shfl_xor(ss, 32);
        if (quad == 0) { sred[w * 128 + gc] = s; sred[512 + w * 128 + gc] = ss; }
    }
    __syncthreads();
    if (t < 128) {
        atomicAdd(&acc_g[t], sred[t] + sred[128 + t] + sred[256 + t] + sred[384 + t]);
        atomicAdd(&acc_g[128 + t], sred[512 + t] + sred[640 + t] + sred[768 + t] + sred[896 + t]);
    }
}

// ======== K2: fused enc2 + quantize + dec1 + stats2 ========
__global__ __launch_bounds__(256) void k_mid(const unsigned short* __restrict__ h1b,
                                             const float* __restrict__ w2e,
                                             const float* __restrict__ b2e,
                                             const float* __restrict__ g1,
                                             const float* __restrict__ be1,
                                             const float* __restrict__ cb,
                                             const unsigned short* __restrict__ cbb,
                                             const float* __restrict__ cn_g,
                                             const float* __restrict__ w1d,
                                             const float* __restrict__ b1d,
                                             unsigned short* __restrict__ h2b,
                                             float* __restrict__ acc_g) {
    // LDS pool (49152 B): see R3 comment (cs overlays As2; sstat overlays cs after sweeps)
    __shared__ __align__(16) char pool[49152];
    unsigned short* As2 = (unsigned short*)pool;          // [m][k] stride 72
    unsigned short* cs  = (unsigned short*)pool;          // [n][k] stride 40
    float*          sstat = (float*)pool;
    unsigned short* Bs2 = (unsigned short*)(pool + 20480);
    unsigned short* Bs3 = (unsigned short*)(pool + 25088);
    unsigned short* zs  = (unsigned short*)(pool + 35328);
    float* cn  = (float*)(pool + 45568);
    float* scl = (float*)(pool + 46592);
    float* shf = (float*)(pool + 47104);
    float* red = (float*)(pool + 47616);
    int* topicsL = (int*)(pool + 48640);

    const int t = threadIdx.x;
    const int w = t >> 6, lane = t & 63, quad = lane >> 4, lcol = lane & 15;
    const int row0 = blockIdx.x << 7;

    if (t < 128) {
        float mu = acc_g[t] * (1.f / 65536.f);
        float var = fmaf(-mu, mu, acc_g[128 + t] * (1.f / 65536.f));
        float s = g1[t] * rsqrtf(var + 1e-5f);
        scl[t] = s;
        shf[t] = fmaf(-mu, s, be1[t]);
    }
#pragma unroll
    for (int i = 0; i < 16; ++i) {
        int idx = (i << 8) + t;
        int n = idx & 127, k = idx >> 7;
        Bs3[n * 40 + k] = f2bf(w1d[k * 128 + n]);
    }
#pragma unroll
    for (int i = 0; i < 16; ++i) {
        int idx = (i << 8) + t;
        int n = idx & 31, k = idx >> 5;
        Bs2[n * 72 + k] = f2bf(w2e[k * 32 + n]);
    }
    __syncthreads();
    // As2 = bn_relu(h1b tile)
#pragma unroll
    for (int i = 0; i < 8; ++i) {
        int fidx = (i << 8) + t;
        int r = fidx >> 4, kq = (fidx & 15) << 3;
        uint4 raw = *(const uint4*)(h1b + (size_t)(row0 + r) * 128 + kq);
        unsigned pv[4] = {raw.x, raw.y, raw.z, raw.w};
        unsigned ov[4];
#pragma unroll
        for (int j = 0; j < 4; ++j) {
            float lo, hi;
            unpack2(pv[j], lo, hi);
            int k = kq + 2 * j;
            lo = fmaxf(fmaf(lo, scl[k], shf[k]), 0.f);
            hi = fmaxf(fmaf(hi, scl[k + 1], shf[k + 1]), 0.f);
            ov[j] = pack2(lo, hi);
        }
        *(uint4*)&As2[r * 72 + kq] = make_uint4(ov[0], ov[1], ov[2], ov[3]);
    }
    __syncthreads();
    // z-GEMM: 32 rows/wave x 32 cols, K=128
    f4a zacc[2][2];
#pragma unroll
    for (int i = 0; i < 2; ++i)
#pragma unroll
        for (int j = 0; j < 2; ++j) zacc[i][j] = (f4a){0.f, 0.f, 0.f, 0.f};
#pragma unroll
    for (int kc = 0; kc < 4; ++kc) {
        const bf8 a0 = *(const bf8*)&As2[(w * 32 + lcol) * 72 + (kc << 5) + (quad << 3)];
        const bf8 a1 = *(const bf8*)&As2[(w * 32 + 16 + lcol) * 72 + (kc << 5) + (quad << 3)];
        const bf8 b0 = *(const bf8*)&Bs2[lcol * 72 + (kc << 5) + (quad << 3)];
        const bf8 b1v = *(const bf8*)&Bs2[(16 + lcol) * 72 + (kc << 5) + (quad << 3)];
        zacc[0][0] = __builtin_amdgcn_mfma_f32_16x16x32_bf16(a0, b0, zacc[0][0], 0, 0, 0);
        zacc[0][1] = __builtin_amdgcn_mfma_f32_16x16x32_bf16(a0, b1v, zacc[0][1], 0, 0, 0);
        zacc[1][0] = __builtin_amdgcn_mfma_f32_16x16x32_bf16(a1, b0, zacc[1][0], 0, 0, 0);
        zacc[1][1] = __builtin_amdgcn_mfma_f32_16x16x32_bf16(a1, b1v, zacc[1][1], 0, 0, 0);
    }
    // bias; keep fp32 z in regs for exact recompute; bf16 z into zs (A-layout)
    const float b2lo = b2e[lcol], b2hi = b2e[16 + lcol];
    float zf0[2][4], zf1[2][4];
#pragma unroll
    for (int mt = 0; mt < 2; ++mt) {
#pragma unroll
        for (int r = 0; r < 4; ++r) {
            float v0 = zacc[mt][0][r] + b2lo;
            float v1 = zacc[mt][1][r] + b2hi;
            zf0[mt][r] = v0;
            zf1[mt][r] = v1;
            int row = w * 32 + mt * 16 + (quad << 2) + r;
            zs[row * 40 + lcol] = f2bf(v0);
            zs[row * 40 + 16 + lcol] = f2bf(v1);
        }
    }
    __syncthreads();
    // quant sweep (bf16 proxy, argmin only)
    bf8 af[2];
    af[0] = *(const bf8*)&zs[(w * 32 + lcol) * 40 + (quad << 3)];
    af[1] = *(const bf8*)&zs[(w * 32 + 16 + lcol) * 40 + (quad << 3)];
    float best[2][4];
    int bidx[2][4];
#pragma unroll
    for (int mt = 0; mt < 2; ++mt)
#pragma unroll
        for (int r = 0; r < 4; ++r) { best[mt][r] = 3.4e38f; bidx[mt][r] = 0; }
    const f4a zero4 = {0.f, 0.f, 0.f, 0.f};

    for (int cp = 0; cp < 4; ++cp) {
        __syncthreads();
#pragma unroll
        for (int i = 0; i < 4; ++i) {   // b128 copy of prepped bf16 codebook
            int idx = (i << 8) + t;
            int r = idx >> 2, kq = (idx & 3) << 3;
            *(uint4*)&cs[r * 40 + kq] = *(const uint4*)(cbb + (size_t)((cp << 8) + r) * 32 + kq);
        }
        cn[t] = cn_g[(cp << 8) + t];
        __syncthreads();
        bf8 bb = *(const bf8*)&cs[lcol * 40 + (quad << 3)];
        float cnv = cn[lcol];
        for (int ch = 0; ch < 16; ++ch) {
            const int nn = ((ch + 1) & 15) << 4;
            const bf8 bb_n = *(const bf8*)&cs[(nn + lcol) * 40 + (quad << 3)];
            const float cn_n = cn[nn + lcol];
            const int cidx = (cp << 8) + (ch << 4) + lcol;
#pragma unroll
            for (int mt = 0; mt < 2; ++mt) {
                f4a a = __builtin_amdgcn_mfma_f32_16x16x32_bf16(af[mt], bb, zero4, 0, 0, 0);
#pragma unroll
                for (int r = 0; r < 4; ++r) {
                    float d = fmaf(-2.f, a[r], cnv);   // proxy: cn - 2 z.c
                    if (d < best[mt][r]) { best[mt][r] = d; bidx[mt][r] = cidx; }
                }
            }
            bb = bb_n; cnv = cn_n;
        }
    }
    // cross-lane argmin (first-index tie-break); butterfly -> all 16 lanes converge
#pragma unroll
    for (int off = 1; off < 16; off <<= 1) {
#pragma unroll
        for (int mt = 0; mt < 2; ++mt)
#pragma unroll
            for (int r = 0; r < 4; ++r) {
                float ob = __shfl_xor(best[mt][r], off);
                int oi = __shfl_xor(bidx[mt][r], off);
                if (ob < best[mt][r] || (ob == best[mt][r] && oi < bidx[mt][r])) {
                    best[mt][r] = ob; bidx[mt][r] = oi;
                }
            }
    }
    // exact fp32 distance of the SELECTED codeword (kills selection bias):
    // each lane holds cols lcol & 16+lcol of fp32 z; gather cb fp32, reduce over 16 lanes.
    float lsum = 0.f;
#pragma unroll
    for (int mt = 0; mt < 2; ++mt) {
#pragma unroll
        for (int r = 0; r < 4; ++r) {
            const int ti = bidx[mt][r];
            const float* cp_ = cb + (size_t)ti * 32;
            float d0 = zf0[mt][r] - cp_[lcol];
            float d1 = zf1[mt][r] - cp_[16 + lcol];
            float p = fmaf(d0, d0, d1 * d1);
            p += __shfl_xor(p, 1); p += __shfl_xor(p, 2);
            p += __shfl_xor(p, 4); p += __shfl_xor(p, 8);
            if (lcol == 0) {
                topicsL[w * 32 + mt * 16 + (quad << 2) + r] = ti;
                lsum += p;
            }
        }
    }
    red[t] = lsum;
    __syncthreads();
    for (int s = 128; s > 0; s >>= 1) {
        if (t < s) red[t] += red[t + s];
        __syncthreads();
    }
    if (t == 0) atomicAdd(acc_g + 512, red[0]);

    // gather selected codewords into zs region (As3)
#pragma unroll
    for (int i = 0; i < 4; ++i) {
        int fidx = (i << 8) + t;
        int r = fidx >> 3, kq = (fidx & 7) << 2;
        float4 v = *(const float4*)(cb + (size_t)topicsL[r] * 32 + kq);
        *(uint2*)&zs[r * 40 + kq] = make_uint2(pack2(v.x, v.y), pack2(v.z, v.w));
    }
    __syncthreads();
    // dec1 GEMM: h2 = As3[128x32] @ Bs3^T + b1d, K=32
    f4a dacc[2][8];
#pragma unroll
    for (int i = 0; i < 2; ++i)
#pragma unroll
        for (int j = 0; j < 8; ++j) dacc[i][j] = (f4a){0.f, 0.f, 0.f, 0.f};
    const bf8 da0 = *(const bf8*)&zs[(w * 32 + lcol) * 40 + (quad << 3)];
    const bf8 da1 = *(const bf8*)&zs[(w * 32 + 16 + lcol) * 40 + (quad << 3)];
#pragma unroll
    for (int nt = 0; nt < 8; ++nt) {
        const bf8 bb = *(const bf8*)&Bs3[(nt * 16 + lcol) * 40 + (quad << 3)];
        dacc[0][nt] = __builtin_amdgcn_mfma_f32_16x16x32_bf16(da0, bb, dacc[0][nt], 0, 0, 0);
        dacc[1][nt] = __builtin_amdgcn_mfma_f32_16x16x32_bf16(da1, bb, dacc[1][nt], 0, 0, 0);
    }
    __syncthreads();   // zs/Bs3 reads done; sstat (aliases pool base) written next
#pragma unroll
    for (int nt = 0; nt < 8; ++nt) {
        const int gc = (nt << 4) + lcol;
        const float bias = b1d[gc];
        float s = 0.f, ss = 0.f;
#pragma unroll
        for (int mt = 0; mt < 2; ++mt) {
            const int rbase = row0 + w * 32 + mt * 16 + (quad << 2);
#pragma unroll
            for (int r = 0; r < 4; ++r) {
                float v = dacc[mt][nt][r] + bias;
                h2b[(size_t)(rbase + r) * 128 + gc] = f2bf(v);
                s += v;
                ss = fmaf(v, v, ss);
            }
        }
        s += __shfl_xor(s, 16);  s += __shfl_xor(s, 32);
        ss += __shfl_xor(ss, 16); ss += __shfl_xor(ss, 32);
        if (quad == 0) { sstat[w * 128 + gc] = s; sstat[512 + w * 128 + gc] = ss; }
    }
    __syncthreads();
    if (t < 128) {
        atomicAdd(&acc_g[256 + t], sstat[t] + sstat[128 + t] + sstat[256 + t] + sstat[384 + t]);
        atomicAdd(&acc_g[384 + t], sstat[512 + t] + sstat[640 + t] + sstat[768 + t] + sstat[896 + t]);
    }
}

// ======== K3: X_ = relu(bn(h2b))@dw2 + db2 ; accumulate sum((X_-X)^2) ========
__global__ __launch_bounds__(512) void k_dec2(const unsigned short* __restrict__ h2b,
                                              float* acc_g,
                                              const float* __restrict__ g,
                                              const float* __restrict__ be,
                                              const float* __restrict__ w2,
                                              const float* __restrict__ b2,
                                              const float* __restrict__ X) {
    __shared__ unsigned short As[128 * 40];
    __shared__ unsigned short Bs[256 * 40];
    __shared__ float scl[128], shf[128];
    __shared__ float red[512];
    const int t = threadIdx.x;
    if (t < 128) {
        float mu = acc_g[256 + t] * (1.f / 65536.f);
        float var = fmaf(-mu, mu, acc_g[384 + t] * (1.f / 65536.f));
        float s = g[t] * rsqrtf(var + 1e-5f);
        scl[t] = s;
        shf[t] = fmaf(-mu, s, be[t]);
    }
    const int row0 = blockIdx.x << 7;
    const int col0 = blockIdx.y << 8;
    const int w = t >> 6, lane = t & 63, quad = lane >> 4, lcol = lane & 15;
    const int wm = w & 1, wn = w >> 1;
    f4a acc[4][4];
#pragma unroll
    for (int i = 0; i < 4; i++)
#pragma unroll
        for (int j = 0; j < 4; j++) acc[i][j] = (f4a){0.f, 0.f, 0.f, 0.f};
    __syncthreads();

    const int bn = t & 255, bkg = t >> 8;
    const int ar = t >> 2, akq = (t & 3) << 3;
    for (int c = 0; c < 4; ++c) {
        const int k0 = c << 5;
        if (c) __syncthreads();
        {
            uint4 raw = *(const uint4*)(h2b + (size_t)(row0 + ar) * 128 + k0 + akq);
            unsigned pv[4] = {raw.x, raw.y, raw.z, raw.w};
            unsigned ov[4];
#pragma unroll
            for (int j = 0; j < 4; ++j) {
                float lo, hi;
                unpack2(pv[j], lo, hi);
                int k = k0 + akq + 2 * j;
                lo = fmaxf(fmaf(lo, scl[k], shf[k]), 0.f);
                hi = fmaxf(fmaf(hi, scl[k + 1], shf[k + 1]), 0.f);
                ov[j] = pack2(lo, hi);
            }
            *(uint4*)&As[ar * 40 + akq] = make_uint4(ov[0], ov[1], ov[2], ov[3]);
        }
#pragma unroll
        for (int i = 0; i < 4; ++i) {
            int k = (bkg << 4) + (i << 2);
            const float* p = w2 + (size_t)(k0 + k) * 512 + col0 + bn;
            float a0 = p[0], a1 = p[512], a2 = p[1024], a3 = p[1536];
            *(uint2*)&Bs[bn * 40 + k] = make_uint2(pack2(a0, a1), pack2(a2, a3));
        }
        __syncthreads();
        bf8 af[4];
#pragma unroll
        for (int mt = 0; mt < 4; ++mt)
            af[mt] = *(const bf8*)&As[(wm * 64 + mt * 16 + lcol) * 40 + (quad << 3)];
#pragma unroll
        for (int nt = 0; nt < 4; ++nt) {
            const bf8 bb = *(const bf8*)&Bs[(wn * 64 + nt * 16 + lcol) * 40 + (quad << 3)];
#pragma unroll
            for (int mt = 0; mt < 4; ++mt)
                acc[mt][nt] = __builtin_amdgcn_mfma_f32_16x16x32_bf16(af[mt], bb, acc[mt][nt], 0, 0, 0);
        }
    }
    float lsum = 0.f;
#pragma unroll
    for (int nt = 0; nt < 4; ++nt) {
        const int gc = col0 + wn * 64 + nt * 16 + lcol;
        const float bias = b2[gc];
#pragma unroll
        for (int mt = 0; mt < 4; ++mt) {
            const int rbase = row0 + wm * 64 + mt * 16 + (quad << 2);
#pragma unroll
            for (int r = 0; r < 4; ++r) {
                float val = acc[mt][nt][r] + bias;
                float d = val - X[(size_t)(rbase + r) * 512 + gc];
                lsum = fmaf(d, d, lsum);
            }
        }
    }
    red[t] = lsum;
    __syncthreads();
    for (int s = 256; s > 0; s >>= 1) {
        if (t < s) red[t] += red[t + s];
        __syncthreads();
    }
    if (t == 0) atomicAdd(acc_g + 513, red[0]);
}

__global__ void k_final(const float* __restrict__ acc, float* __restrict__ out) {
    if (threadIdx.x == 0) out[0] = 2.f * acc[512] + sqrtf(acc[513]);
}

extern "C" void kernel_launch(void* const* d_in, const int* in_sizes, int n_in,
                              void* d_out, int out_size, void* d_ws, size_t ws_size,
                              hipStream_t stream) {
    const float* X       = (const float*)d_in[0];
    const float* enc_w1  = (const float*)d_in[1];
    const float* enc_b1  = (const float*)d_in[2];
    const float* enc_g1  = (const float*)d_in[3];
    const float* enc_be1 = (const float*)d_in[4];
    const float* enc_w2  = (const float*)d_in[5];
    const float* enc_b2  = (const float*)d_in[6];
    const float* dec_w1  = (const float*)d_in[7];
    const float* dec_b1  = (const float*)d_in[8];
    const float* dec_g1  = (const float*)d_in[9];
    const float* dec_be1 = (const float*)d_in[10];
    const float* dec_w2  = (const float*)d_in[11];
    const float* dec_b2  = (const float*)d_in[12];
    const float* cb      = (const float*)d_in[13];
    float* out = (float*)d_out;

    float* acc = (float*)d_ws;                               // 1024 f32
    unsigned short* cbb = (unsigned short*)(acc + 1024);     // 1024*32 bf16
    float* cn_g = (float*)(cbb + 1024 * 32);                 // 1024 f32
    unsigned short* h1b = (unsigned short*)(cn_g + 1024);    // 65536*128 bf16
    unsigned short* h2b = h1b + (size_t)65536 * 128;         // 65536*128 bf16

    k_prep<<<5, 256, 0, stream>>>(cb, acc, cbb, cn_g);
    k_enc1<<<512, 256, 0, stream>>>(X, enc_w1, enc_b1, h1b, acc);
    k_mid<<<512, 256, 0, stream>>>(h1b, enc_w2, enc_b2, enc_g1, enc_be1,
                                   cb, cbb, cn_g, dec_w1, dec_b1, h2b, acc);
    k_dec2<<<dim3(512, 2), 512, 0, stream>>>(h2b, acc, dec_g1, dec_be1, dec_w2, dec_b2, X);
    k_final<<<1, 64, 0, stream>>>(acc, out);
}